// Round 11
// baseline (2372.584 us; speedup 1.0000x reference)
//
#include <hip/hip_runtime.h>

// ---------------------------------------------------------------------------
// MusicLSTM: B=256, T=2048, I=2, H=128 (4H=512 gates), P=129 pitches.
//   prep_k  : note_W+dur_W -> f16 Wn[144][128] in ws
//   lstm5_k : 16 WGs x 16 batches, 512 thr (8 waves, 2/SIMD). Per step ONE
//             MFMA GEMM gates[16 batches x 512] = H[16x128] . W_hh^T with the
//             M dimension FULLY filled by batches (r8/r10 broadcast h to all
//             16 M rows -> 15/16 of matrix-pipe time wasted; that 512 cyc/
//             step/SIMD was the wall). Wave w owns n-tiles {w+8tt}: lane
//             (p,q) gets all 4 gates of col j=16w+p for batches 4q+r in its
//             own acc regs (static indexing only). 4 cell updates per lane.
//             h in padded LDS [16][136] (272B stride, proj_k's measured
//             conflict-free pattern), double buffered. x staged in 64-step
//             chunks. One raw s_barrier per step (lgkm-only drain; global hs
//             stores stay in flight).
//   proj_k  : MFMA f16 GEMM over hs -> note/dur logits, masked rows zeroed.
// Fragment layout conventions (verified by the passing proj_k / r10):
//   A: lane l holds A[m=l&15][k=32*kt+8*(l>>4)+e], e=0..7
//   B: lane l holds B[n=l&15][k=32*kt+8*(l>>4)+e]
//   D: lane l reg r holds D[m=(l>>4)*4+r][n=l&15]
// ---------------------------------------------------------------------------

typedef _Float16 f16;
typedef _Float16 f16x8 __attribute__((ext_vector_type(8)));
typedef float    f32x4 __attribute__((ext_vector_type(4)));

#define B_  256
#define T_  2048
#define H_  128
#define P_  129
#define NB  16

static constexpr size_t NOTE_N   = (size_t)B_ * T_ * P_;
static constexpr size_t DUR_BASE = NOTE_N;
static constexpr size_t HT_BASE  = DUR_BASE + (size_t)B_ * T_;
static constexpr size_t CT_BASE  = HT_BASE + (size_t)B_ * H_;

#if defined(__has_builtin)
#if __has_builtin(__builtin_amdgcn_exp2f)
#define EXP2F(x) __builtin_amdgcn_exp2f(x)
#endif
#endif
#ifndef EXP2F
#define EXP2F(x) __expf((x) * 0.6931471805599453f)
#endif

__device__ __forceinline__ float fast_rcp(float x) { return __builtin_amdgcn_rcpf(x); }

__device__ __forceinline__ float sigmoid_f(float x) {
    float e = EXP2F(-1.44269504f * x);
    return fast_rcp(1.f + e);
}
__device__ __forceinline__ float tanh_f(float x) {
    float e = EXP2F(2.885390082f * x);
    return (e - 1.f) * fast_rcp(e + 1.f);
}

// hs row bt lives at the front of note row bt, rounded up to 16B alignment.
__device__ __forceinline__ f16* hs_row(float* out, int bt) {
    size_t byteoff = ((size_t)bt * (P_ * 4) + 15) & ~(size_t)15;
    return (f16*)((char*)out + byteoff);
}

// ---------------------------------------------------------------------------
__global__ __launch_bounds__(256) void prep_k(const float* __restrict__ note_W,
                                              const float* __restrict__ dur_W,
                                              f16* __restrict__ Wn) {
    int i = threadIdx.x + blockIdx.x * 256;
    if (i >= 144 * 128) return;
    int row = i >> 7, k = i & 127;
    float v = 0.f;
    if (row < 129)       v = note_W[row * 128 + k];
    else if (row == 129) v = dur_W[k];
    Wn[i] = (f16)v;
}

// ---------------------------------------------------------------------------
__global__ __launch_bounds__(512, 2) void lstm5_k(const float* __restrict__ x,
                                                  const int* __restrict__ lengths,
                                                  const float* __restrict__ W_ih,
                                                  const float* __restrict__ W_hh,
                                                  float* __restrict__ out) {
    __shared__ __align__(16) f16   h_sh[2][NB][136];  // 8.7 KB, padded rows
    __shared__ __align__(16) float xs[64][NB][2];     // 8 KB x-chunk

    const int tid = threadIdx.x;
    const int g   = blockIdx.x;        // batch group: batches g*16..g*16+15
    const int bg  = g * NB;
    const int w   = tid >> 6;          // wave 0..7
    const int l   = tid & 63;
    const int p   = l & 15;
    const int q   = l >> 4;
    const int j   = 16 * w + p;        // this lane's hidden column

    // B-fragments: gate rows c = j + 128*tt (tt = i,f,g,o), k-slice 8q..8q+7
    f16x8 Bf[4][4];
    float wxx[4], wxy[4];
#pragma unroll
    for (int tt = 0; tt < 4; tt++) {
        const int c = j + 128 * tt;
        const float* wr = W_hh + (size_t)c * H_ + 8 * q;
#pragma unroll
        for (int kt = 0; kt < 4; kt++) {
            float4 v1 = *(const float4*)(wr + 32 * kt);
            float4 v2 = *(const float4*)(wr + 32 * kt + 4);
            f16x8 f;
            f[0] = (f16)v1.x; f[1] = (f16)v1.y; f[2] = (f16)v1.z; f[3] = (f16)v1.w;
            f[4] = (f16)v2.x; f[5] = (f16)v2.y; f[6] = (f16)v2.z; f[7] = (f16)v2.w;
            Bf[tt][kt] = f;
        }
        wxx[tt] = W_ih[2 * c];
        wxy[tt] = W_ih[2 * c + 1];
    }

    const int len0 = lengths[bg + 4 * q + 0];
    const int len1 = lengths[bg + 4 * q + 1];
    const int len2 = lengths[bg + 4 * q + 2];
    const int len3 = lengths[bg + 4 * q + 3];
    int maxlen = 0;
    for (int k = 0; k < NB; k++) maxlen = max(maxlen, lengths[bg + k]);

    // zero both h buffers (incl. padding)
    for (int i = tid; i < 2 * NB * 136; i += 512) ((f16*)h_sh)[i] = (f16)0.f;

    // incremental hs store pointers, one per handled batch
    char* hp0 = (char*)out + (size_t)(bg + 4 * q + 0) * (T_ * 516ULL) + 2 * j;
    char* hp1 = (char*)out + (size_t)(bg + 4 * q + 1) * (T_ * 516ULL) + 2 * j;
    char* hp2 = (char*)out + (size_t)(bg + 4 * q + 2) * (T_ * 516ULL) + 2 * j;
    char* hp3 = (char*)out + (size_t)(bg + 4 * q + 3) * (T_ * 516ULL) + 2 * j;

    const f32x4 z4 = {0.f, 0.f, 0.f, 0.f};
    float c0 = 0.f, c1 = 0.f, c2 = 0.f, c3 = 0.f;
    float h0 = 0.f, h1 = 0.f, h2 = 0.f, h3 = 0.f;

    for (int t = 0; t < maxlen; t++) {
        if ((t & 63) == 0) {
            // refill x chunk [t, t+64). Prior chunk reads drained at the
            // previous step's barrier; full sync after writes before use.
            const int b = tid & 15, tp = tid >> 4;   // tp 0..31
            float4 v = *(const float4*)(x + (size_t)(bg + b) * (T_ * 2)
                                          + (size_t)(t + 2 * tp) * 2);
            *(float2*)&xs[2 * tp][b][0]     = make_float2(v.x, v.y);
            *(float2*)&xs[2 * tp + 1][b][0] = make_float2(v.z, v.w);
            __syncthreads();
        }
        const int cur = t & 1;
        const int nxt = cur ^ 1;

        // A-fragments: batch p's h slice (proj-pattern padded reads)
        f16x8 Af[4];
#pragma unroll
        for (int kt = 0; kt < 4; kt++)
            Af[kt] = *(const f16x8*)(&h_sh[cur][p][32 * kt + 8 * q]);

        // x for this lane's 4 batches (two 16B broadcast reads)
        const float4 xq0 = *(const float4*)(&xs[t & 63][4 * q][0]);
        const float4 xq1 = *(const float4*)(&xs[t & 63][4 * q + 2][0]);

        f32x4 acc[4];
#pragma unroll
        for (int tt = 0; tt < 4; tt++)
            acc[tt] = __builtin_amdgcn_mfma_f32_16x16x32_f16(Af[0], Bf[tt][0], z4, 0, 0, 0);
#pragma unroll
        for (int kt = 1; kt < 4; kt++) {
#pragma unroll
            for (int tt = 0; tt < 4; tt++)
                acc[tt] = __builtin_amdgcn_mfma_f32_16x16x32_f16(
                    Af[kt], Bf[tt][kt], acc[tt], 0, 0, 0);
        }

        // 4 cell updates, all-static indexing (rule #20)
#define UPDATE(R, XVX, XVY, CV, HV, LEN, HP) {                                   \
        float G0 = acc[0][R] + __builtin_fmaf(wxy[0], XVY, wxx[0] * (XVX));      \
        float G1 = acc[1][R] + __builtin_fmaf(wxy[1], XVY, wxx[1] * (XVX));      \
        float G2 = acc[2][R] + __builtin_fmaf(wxy[2], XVY, wxx[2] * (XVX));      \
        float G3 = acc[3][R] + __builtin_fmaf(wxy[3], XVY, wxx[3] * (XVX));      \
        float ig = sigmoid_f(G0), fg = sigmoid_f(G1);                            \
        float gg = tanh_f(G2),    og = sigmoid_f(G3);                            \
        float cn = __builtin_fmaf(fg, CV, ig * gg);                              \
        float hn = og * tanh_f(fminf(fmaxf(cn, -15.f), 15.f));                   \
        bool m = (t < LEN);                                                      \
        CV = m ? cn : CV;  HV = m ? hn : HV;                                     \
        f16 h16 = (f16)HV;                                                       \
        h_sh[nxt][4 * q + R][j] = h16;                                           \
        if (m) *(f16*)HP = h16;                                                  \
        HP += 512 + (((t & 3) == 0) ? 16 : 0);                                   \
    }
        UPDATE(0, xq0.x, xq0.y, c0, h0, len0, hp0)
        UPDATE(1, xq0.z, xq0.w, c1, h1, len1, hp1)
        UPDATE(2, xq1.x, xq1.y, c2, h2, len2, hp2)
        UPDATE(3, xq1.z, xq1.w, c3, h3, len3, hp3)
#undef UPDATE

        // drain LDS only; global hs stores remain outstanding
        asm volatile("s_waitcnt lgkmcnt(0)" ::: "memory");
        __builtin_amdgcn_sched_barrier(0);
        __builtin_amdgcn_s_barrier();
        __builtin_amdgcn_sched_barrier(0);
    }

    out[HT_BASE + (size_t)(bg + 4 * q + 0) * H_ + j] = h0;
    out[HT_BASE + (size_t)(bg + 4 * q + 1) * H_ + j] = h1;
    out[HT_BASE + (size_t)(bg + 4 * q + 2) * H_ + j] = h2;
    out[HT_BASE + (size_t)(bg + 4 * q + 3) * H_ + j] = h3;
    out[CT_BASE + (size_t)(bg + 4 * q + 0) * H_ + j] = c0;
    out[CT_BASE + (size_t)(bg + 4 * q + 1) * H_ + j] = c1;
    out[CT_BASE + (size_t)(bg + 4 * q + 2) * H_ + j] = c2;
    out[CT_BASE + (size_t)(bg + 4 * q + 3) * H_ + j] = c3;
}

// ---------------------------------------------------------------------------
// Projection GEMM: C[bt, n] = hs[bt,:] . Wn[n,:] + bias, masked by t<len.
__global__ __launch_bounds__(256) void proj_k(const int* __restrict__ lengths,
                                              const f16* __restrict__ Wn,
                                              const float* __restrict__ note_b,
                                              const float* __restrict__ dur_b,
                                              float* __restrict__ out) {
    __shared__ __align__(16) f16 wn_sh[144 * 136];

    const int tid = threadIdx.x;
    {
        unsigned int* dst = (unsigned int*)wn_sh;
        const unsigned int* src = (const unsigned int*)Wn;
        for (int w = tid; w < 144 * 64; w += 256) {
            int row = w >> 6, cw = w & 63;
            dst[row * 68 + cw] = src[w];
        }
    }
    __syncthreads();

    const int wv = tid >> 6;
    const int l = tid & 63;
    const int tile = blockIdx.x * 4 + wv;
    const int bt0 = tile * 16;
    const int b = bt0 >> 11;
    const int t0 = bt0 & 2047;
    const int len = lengths[b];
    const int r16 = l & 15, q = l >> 4;

    f32x4 acc[9];
#pragma unroll
    for (int nf = 0; nf < 9; nf++) acc[nf] = f32x4{0.f, 0.f, 0.f, 0.f};

    const bool live = (t0 < len);
    if (live) {
        f16x8 a[4];
        {
            const f16* ar = hs_row(out, bt0 + r16);
#pragma unroll
            for (int kk = 0; kk < 4; kk++)
                a[kk] = *(const f16x8*)(ar + kk * 32 + q * 8);
        }
#pragma unroll
        for (int nf = 0; nf < 9; nf++) {
            const f16* brow = wn_sh + (nf * 16 + r16) * 136 + q * 8;
#pragma unroll
            for (int kk = 0; kk < 4; kk++) {
                f16x8 bb = *(const f16x8*)(brow + kk * 32);
                acc[nf] = __builtin_amdgcn_mfma_f32_16x16x32_f16(a[kk], bb, acc[nf], 0, 0, 0);
            }
        }
    }

#pragma unroll
    for (int nf = 0; nf < 9; nf++) {
        int col = nf * 16 + r16;
        float bias = 0.f;
        if (col < 129)       bias = note_b[col];
        else if (col == 129) bias = dur_b[0];
#pragma unroll
        for (int r = 0; r < 4; r++) {
            int rowbt = bt0 + q * 4 + r;
            int t = t0 + q * 4 + r;
            float v = (t < len) ? (acc[nf][r] + bias) : 0.f;
            if (col < 129)
                out[(size_t)rowbt * P_ + col] = v;
            else if (col == 129)
                out[DUR_BASE + rowbt] = v;
        }
    }
}

// ---------------------------------------------------------------------------
extern "C" void kernel_launch(void* const* d_in, const int* in_sizes, int n_in,
                              void* d_out, int out_size, void* d_ws, size_t ws_size,
                              hipStream_t stream) {
    const float* x       = (const float*)d_in[0];
    const int*   lengths = (const int*)d_in[1];
    const float* W_ih    = (const float*)d_in[2];
    const float* W_hh    = (const float*)d_in[3];
    const float* note_W  = (const float*)d_in[4];
    const float* note_b  = (const float*)d_in[5];
    const float* dur_W   = (const float*)d_in[6];
    const float* dur_b   = (const float*)d_in[7];
    float* out = (float*)d_out;
    f16* Wn = (f16*)d_ws;

    prep_k<<<72, 256, 0, stream>>>(note_W, dur_W, Wn);
    lstm5_k<<<B_ / NB, 512, 0, stream>>>(x, lengths, W_ih, W_hh, out);
    proj_k<<<(B_ * T_) / 64, 256, 0, stream>>>(lengths, Wn, note_b, dur_b, out);
}

// Round 12
// 1127.337 us; speedup vs baseline: 2.1046x; 2.1046x over previous
//
#include <hip/hip_runtime.h>

// ---------------------------------------------------------------------------
// MusicLSTM: B=256, T=2048, I=2, H=128 (4H=512 gates), P=129 pitches.
//   prep_k  : note_W+dur_W -> f16 Wn[144][128] in ws
//   lstm6_k : 1 WG (256 thr, 4 waves = 1/SIMD) per batch. Gate matvec via
//             v_dot2_f32_f16: thread (j=tid>>1, kh=tid&1) computes ALL 4
//             gates of column j over K-half kh (128 fdot2 in 8x16 chains),
//             one DPP xor1 reduce per gate, input projection post-reduce.
//             Rationale: MFMA matvec has a hard floor of 32 MFMA/SIMD/step
//             (~590 cyc) since weights only enter via A (512 useful MACs per
//             instr); dot2 does the same matvec in ~256 issue cyc/SIMD.
//             Weights live in a 128-VGPR union (f16x8-backed, static unroll
//             indices only -- rule #20), kept resident by 256thr+(256,1)
//             (r10 proved this pattern holds a 128-VGPR array; r4-r6's f16x2
//             arrays at 512thr were demoted -> per-step L2 reloads).
//             One raw s_barrier per step (lgkm drain only; global hs stores
//             stay in flight). h double-buffered in LDS; x in 128-step
//             chunks; incremental hs store addressing.
//   proj_k  : MFMA f16 GEMM over hs -> note/dur logits, masked rows zeroed.
// ---------------------------------------------------------------------------

typedef _Float16 f16;
typedef _Float16 f16x2 __attribute__((ext_vector_type(2)));
typedef _Float16 f16x8 __attribute__((ext_vector_type(8)));
typedef float    f32x4 __attribute__((ext_vector_type(4)));

#define B_  256
#define T_  2048
#define H_  128
#define P_  129

static constexpr size_t NOTE_N   = (size_t)B_ * T_ * P_;
static constexpr size_t DUR_BASE = NOTE_N;
static constexpr size_t HT_BASE  = DUR_BASE + (size_t)B_ * T_;
static constexpr size_t CT_BASE  = HT_BASE + (size_t)B_ * H_;

#if defined(__has_builtin)
#if __has_builtin(__builtin_amdgcn_fdot2)
#define HAVE_FDOT2 1
#endif
#if __has_builtin(__builtin_amdgcn_exp2f)
#define EXP2F(x) __builtin_amdgcn_exp2f(x)
#endif
#endif
#ifndef EXP2F
#define EXP2F(x) __expf((x) * 0.6931471805599453f)
#endif

__device__ __forceinline__ float dot2_acc(f16x2 a, f16x2 b, float c) {
#ifdef HAVE_FDOT2
    return __builtin_amdgcn_fdot2(a, b, c, false);
#else
    return c + (float)a[0] * (float)b[0] + (float)a[1] * (float)b[1];
#endif
}

__device__ __forceinline__ float fast_rcp(float x) { return __builtin_amdgcn_rcpf(x); }

__device__ __forceinline__ float sigmoid_f(float x) {
    float e = EXP2F(-1.44269504f * x);
    return fast_rcp(1.f + e);
}
__device__ __forceinline__ float tanh_f(float x) {
    float e = EXP2F(2.885390082f * x);
    return (e - 1.f) * fast_rcp(e + 1.f);
}

// pair all-reduce (lanes 2j/2j+1) via DPP quad_perm [1,0,3,2]
__device__ __forceinline__ float pair_allsum(float v) {
    int a = __float_as_int(v);
    v += __int_as_float(__builtin_amdgcn_mov_dpp(a, 0xB1, 0xF, 0xF, true));
    return v;
}

// hs row bt lives at the front of note row bt, rounded up to 16B alignment.
__device__ __forceinline__ f16* hs_row(float* out, int bt) {
    size_t byteoff = ((size_t)bt * (P_ * 4) + 15) & ~(size_t)15;
    return (f16*)((char*)out + byteoff);
}

// ---------------------------------------------------------------------------
__global__ __launch_bounds__(256) void prep_k(const float* __restrict__ note_W,
                                              const float* __restrict__ dur_W,
                                              f16* __restrict__ Wn) {
    int i = threadIdx.x + blockIdx.x * 256;
    if (i >= 144 * 128) return;
    int row = i >> 7, k = i & 127;
    float v = 0.f;
    if (row < 129)       v = note_W[row * 128 + k];
    else if (row == 129) v = dur_W[k];
    Wn[i] = (f16)v;
}

// ---------------------------------------------------------------------------
__global__ __launch_bounds__(256, 1) void lstm6_k(const float* __restrict__ x,
                                                  const int* __restrict__ lengths,
                                                  const float* __restrict__ W_ih,
                                                  const float* __restrict__ W_hh,
                                                  float* __restrict__ out) {
    __shared__ __align__(16) f16 h_sh[2][H_];   // double-buffered h (512 B)
    __shared__ __align__(8) float2 xs[128];     // x chunk: 128 steps (1 KB)

    const int tid = threadIdx.x;
    const int b = blockIdx.x;
    const int j  = tid >> 1;      // hidden column 0..127
    const int kh = tid & 1;       // K-half: elems [64*kh, 64*kh+64)
    const bool writer = (kh == 0);

    // Per-thread weights: 4 gate rows (c = j + 128g), K-half slice of 64.
    // f16x8-backed union; all v2 indices are unroll-constant (rule #20).
    union WU { f16x8 v8[32]; f16x2 v2[128]; } wu;
    float wix[4], wiy[4];
#pragma unroll
    for (int g = 0; g < 4; g++) {
        const int c = j + 128 * g;
        const float* wr = W_hh + (size_t)c * H_ + 64 * kh;
#pragma unroll
        for (int i = 0; i < 8; i++) {
            float4 v1 = *(const float4*)(wr + 8 * i);
            float4 v2 = *(const float4*)(wr + 8 * i + 4);
            f16x8 f;
            f[0] = (f16)v1.x; f[1] = (f16)v1.y; f[2] = (f16)v1.z; f[3] = (f16)v1.w;
            f[4] = (f16)v2.x; f[5] = (f16)v2.y; f[6] = (f16)v2.z; f[7] = (f16)v2.w;
            wu.v8[8 * g + i] = f;
        }
        wix[g] = W_ih[2 * c];
        wiy[g] = W_ih[2 * c + 1];
    }
    const int len = lengths[b];
    ((f16*)h_sh)[tid] = (f16)0.f;   // zero both buffers (2*128 = 256 = tid range)

    // incremental hs store pointer (row stride pattern 528,512,512,512)
    char* hp = (char*)out + (size_t)b * (T_ * 516ULL) + 2 * j;

    float c_reg = 0.f, h_reg = 0.f;

    for (int t = 0; t < len; t++) {
        if ((t & 127) == 0) {
            // refill x chunk [t, t+128). Full drain barrier, amortized /128.
            __syncthreads();
            if (tid < 128)
                xs[tid] = *(const float2*)(x + (size_t)b * T_ * 2 + (size_t)(t + tid) * 2);
            __syncthreads();
        }
        const int cur = t & 1;

        // this thread's h K-half: 8 x 16B broadcast reads (2 addrs/instr)
        union HU { f16x8 v8[8]; f16x2 v2[32]; } hu;
#pragma unroll
        for (int i = 0; i < 8; i++)
            hu.v8[i] = *(const f16x8*)(&h_sh[cur][64 * kh + 8 * i]);

        // 8 chains of 16 fdot2 (4 gates x 2 sub-chains)
        float a0 = 0.f, a1 = 0.f, a2 = 0.f, a3 = 0.f;
        float b0 = 0.f, b1 = 0.f, b2 = 0.f, b3 = 0.f;
#pragma unroll
        for (int i = 0; i < 16; i++) {
            f16x2 hp0 = hu.v2[i];
            f16x2 hq0 = hu.v2[i + 16];
            a0 = dot2_acc(wu.v2[i],       hp0, a0);
            b0 = dot2_acc(wu.v2[i + 16],  hq0, b0);
            a1 = dot2_acc(wu.v2[i + 32],  hp0, a1);
            b1 = dot2_acc(wu.v2[i + 48],  hq0, b1);
            a2 = dot2_acc(wu.v2[i + 64],  hp0, a2);
            b2 = dot2_acc(wu.v2[i + 80],  hq0, b2);
            a3 = dot2_acc(wu.v2[i + 96],  hp0, a3);
            b3 = dot2_acc(wu.v2[i + 112], hq0, b3);
        }
        a0 += b0; a1 += b1; a2 += b2; a3 += b3;
        // K-half reduce across the lane pair
        a0 = pair_allsum(a0);
        a1 = pair_allsum(a1);
        a2 = pair_allsum(a2);
        a3 = pair_allsum(a3);
        // input projection: identical in both lanes -> add once, post-reduce
        const float2 xv = xs[t & 127];
        a0 += __builtin_fmaf(wiy[0], xv.y, wix[0] * xv.x);
        a1 += __builtin_fmaf(wiy[1], xv.y, wix[1] * xv.x);
        a2 += __builtin_fmaf(wiy[2], xv.y, wix[2] * xv.x);
        a3 += __builtin_fmaf(wiy[3], xv.y, wix[3] * xv.x);

        const float ig = sigmoid_f(a0);
        const float fg = sigmoid_f(a1);
        const float gg = tanh_f(a2);
        const float og = sigmoid_f(a3);
        c_reg = __builtin_fmaf(fg, c_reg, ig * gg);
        h_reg = og * tanh_f(fminf(fmaxf(c_reg, -15.f), 15.f));

        if (writer) {
            const f16 h16 = (f16)h_reg;
            *(f16*)hp = h16;            // global first (stays in flight)
            h_sh[cur ^ 1][j] = h16;     // LDS (lgkm)
        }
        hp += 512 + (((t & 3) == 0) ? 16 : 0);

        // drain LDS only; global hs stores remain outstanding
        asm volatile("s_waitcnt lgkmcnt(0)" ::: "memory");
        __builtin_amdgcn_sched_barrier(0);
        __builtin_amdgcn_s_barrier();
        __builtin_amdgcn_sched_barrier(0);
    }

    if (writer) {
        out[HT_BASE + (size_t)b * H_ + j] = h_reg;
        out[CT_BASE + (size_t)b * H_ + j] = c_reg;
    }
}

// ---------------------------------------------------------------------------
// Projection GEMM: C[bt, n] = hs[bt,:] . Wn[n,:] + bias, masked by t<len.
__global__ __launch_bounds__(256) void proj_k(const int* __restrict__ lengths,
                                              const f16* __restrict__ Wn,
                                              const float* __restrict__ note_b,
                                              const float* __restrict__ dur_b,
                                              float* __restrict__ out) {
    __shared__ __align__(16) f16 wn_sh[144 * 136];

    const int tid = threadIdx.x;
    {
        unsigned int* dst = (unsigned int*)wn_sh;
        const unsigned int* src = (const unsigned int*)Wn;
        for (int w = tid; w < 144 * 64; w += 256) {
            int row = w >> 6, cw = w & 63;
            dst[row * 68 + cw] = src[w];
        }
    }
    __syncthreads();

    const int wv = tid >> 6;
    const int l = tid & 63;
    const int tile = blockIdx.x * 4 + wv;
    const int bt0 = tile * 16;
    const int b = bt0 >> 11;
    const int t0 = bt0 & 2047;
    const int len = lengths[b];
    const int r16 = l & 15, q = l >> 4;

    f32x4 acc[9];
#pragma unroll
    for (int nf = 0; nf < 9; nf++) acc[nf] = f32x4{0.f, 0.f, 0.f, 0.f};

    const bool live = (t0 < len);
    if (live) {
        f16x8 a[4];
        {
            const f16* ar = hs_row(out, bt0 + r16);
#pragma unroll
            for (int kk = 0; kk < 4; kk++)
                a[kk] = *(const f16x8*)(ar + kk * 32 + q * 8);
        }
#pragma unroll
        for (int nf = 0; nf < 9; nf++) {
            const f16* brow = wn_sh + (nf * 16 + r16) * 136 + q * 8;
#pragma unroll
            for (int kk = 0; kk < 4; kk++) {
                f16x8 bb = *(const f16x8*)(brow + kk * 32);
                acc[nf] = __builtin_amdgcn_mfma_f32_16x16x32_f16(a[kk], bb, acc[nf], 0, 0, 0);
            }
        }
    }

#pragma unroll
    for (int nf = 0; nf < 9; nf++) {
        int col = nf * 16 + r16;
        float bias = 0.f;
        if (col < 129)       bias = note_b[col];
        else if (col == 129) bias = dur_b[0];
#pragma unroll
        for (int r = 0; r < 4; r++) {
            int rowbt = bt0 + q * 4 + r;
            int t = t0 + q * 4 + r;
            float v = (t < len) ? (acc[nf][r] + bias) : 0.f;
            if (col < 129)
                out[(size_t)rowbt * P_ + col] = v;
            else if (col == 129)
                out[DUR_BASE + rowbt] = v;
        }
    }
}

// ---------------------------------------------------------------------------
extern "C" void kernel_launch(void* const* d_in, const int* in_sizes, int n_in,
                              void* d_out, int out_size, void* d_ws, size_t ws_size,
                              hipStream_t stream) {
    const float* x       = (const float*)d_in[0];
    const int*   lengths = (const int*)d_in[1];
    const float* W_ih    = (const float*)d_in[2];
    const float* W_hh    = (const float*)d_in[3];
    const float* note_W  = (const float*)d_in[4];
    const float* note_b  = (const float*)d_in[5];
    const float* dur_W   = (const float*)d_in[6];
    const float* dur_b   = (const float*)d_in[7];
    float* out = (float*)d_out;
    f16* Wn = (f16*)d_ws;

    prep_k<<<72, 256, 0, stream>>>(note_W, dur_W, Wn);
    lstm6_k<<<B_, 256, 0, stream>>>(x, lengths, W_ih, W_hh, out);
    proj_k<<<(B_ * T_) / 64, 256, 0, stream>>>(lengths, Wn, note_b, dur_b, out);
}